// Round 5
// baseline (466.982 us; speedup 1.0000x reference)
//
#include <hip/hip_runtime.h>
#include <hip/hip_bf16.h>
#include <math.h>

#define B_  128
#define S_  2048
#define DI  512
#define DC  512

typedef __attribute__((ext_vector_type(8))) __bf16 bf16x8;
typedef __attribute__((ext_vector_type(4))) float  f32x4;
typedef __attribute__((ext_vector_type(8))) unsigned short us8;

__device__ __forceinline__ float fast_tanh(float x) {
    // tanh(x) = 1 - 2/(exp(2x)+1); inf-safe at both ends
    float e = __expf(2.f * x);
    return 1.f - 2.f * __builtin_amdgcn_rcpf(e + 1.f);
}

__device__ __forceinline__ unsigned short f2bf(float f) {
    unsigned int u = __float_as_uint(f);
    u += 0x7FFF + ((u >> 16) & 1);   // RNE
    return (unsigned short)(u >> 16);
}

__device__ __forceinline__ unsigned int pk2(float a, float b) {
    // packed f32x2 -> bf16x2 (v_cvt_pk_bf16_f32), low = a
    union { __hip_bfloat162 h; unsigned int u; } c;
    c.h = __float22bfloat162_rn(make_float2(a, b));
    return c.u;
}

__device__ __forceinline__ float bf2f(unsigned int lo16) {
    return __uint_as_float(lo16 << 16);
}

// q[b][e] = b_in[e] + b_ctx[e] + sum_d input[b][d]*W_in[d][e]; grid (B, 4)
__global__ __launch_bounds__(256) void qb_kernel(
    const float* __restrict__ input, const float* __restrict__ W_in,
    const float* __restrict__ b_in, const float* __restrict__ b_ctx,
    float* __restrict__ qb)
{
    __shared__ float sIn[DI];
    __shared__ float part[2][128];
    int b = blockIdx.x, cg = blockIdx.y, t = threadIdx.x;
    for (int i = t; i < DI; i += 256) sIn[i] = input[b * DI + i];
    __syncthreads();
    int e = cg * 128 + (t & 127);
    int dh = t >> 7;
    float a = 0.f;
    const float* wp = W_in + (size_t)(dh * 256) * DC + e;
    #pragma unroll 4
    for (int d = 0; d < 256; ++d) a += sIn[dh * 256 + d] * wp[(size_t)d * DC];
    part[dh][t & 127] = a;
    __syncthreads();
    if (t < 128) {
        int ee = cg * 128 + t;
        qb[b * DC + ee] = b_in[ee] + b_ctx[ee] + part[0][t] + part[1][t];
    }
}

// Repack W_ctx into MFMA B-fragment order:
// WtF[s][g][lane][j] = bf16(W_ctx[s*32 + (lane>>4)*8 + j][g*16 + (lane&15)])
__global__ __launch_bounds__(256) void wt_kernel(
    const float* __restrict__ W_ctx, unsigned short* __restrict__ WtF)
{
    int tid = blockIdx.x * 256 + threadIdx.x;   // [0, 16*32*64)
    int s   = tid >> 11;
    int rem = tid & 2047;
    int g   = rem >> 6;
    int l   = rem & 63;
    int c   = g * 16 + (l & 15);
    int k0  = s * 32 + (l >> 4) * 8;
    us8 w;
    #pragma unroll
    for (int j = 0; j < 8; ++j)
        w[j] = f2bf(W_ctx[(size_t)(k0 + j) * DC + c]);
    *(us8*)(WtF + (size_t)tid * 8) = w;
}

// Persistent fused score kernel: 256 blocks x 1024 threads (16 waves),
// 16 tiles of 64 rows per block, double-buffered ctx staging.
// Wave (wr, wcol): rows [wr*32,+32), cols [wcol*64,+64).
__global__ __launch_bounds__(1024, 4) void score_kernel(
    const float* __restrict__ ctx,          // [B*S, DC] fp32
    const unsigned short* __restrict__ WtF, // fragment-ordered bf16
    const float* __restrict__ qb,           // [B][DC]
    const float* __restrict__ wsc,          // [DC]
    const int* __restrict__ mask,           // [B*S]
    float* __restrict__ scores_ws,          // [B*S]
    float* __restrict__ pv_ws,              // [ntiles][512]
    float* __restrict__ ml_ws)              // [ntiles][2]
{
    __shared__ __align__(16) unsigned short ctxs[2][64 * 512]; // 2 x 64 KB
    __shared__ float sred[8][64];
    __shared__ float sp[64];
    __shared__ float pvpart[2][512];

    const int t = threadIdx.x;
    const int lane = t & 63;
    const int w = t >> 6;                   // wave 0..15
    const int wr = w >> 3;                  // row half
    const int wcol = w & 7;                 // col slice
    const int lr = lane & 15, half = lane >> 4;

    // staging geometry: thread covers rows {i*16+w}, cols lane*8..+8
    float4 va[4], vb[4];

    // ---- prologue: stage tile0 into buf 0 ----
    {
        const int row0 = blockIdx.x * 64;
        #pragma unroll
        for (int i = 0; i < 4; ++i) {
            const float4* src = (const float4*)(ctx + (size_t)(row0 + i * 16 + w) * DC + lane * 8);
            va[i] = src[0]; vb[i] = src[1];
        }
        #pragma unroll
        for (int i = 0; i < 4; ++i) {
            int r = i * 16 + w;
            uint4 pk4 = {pk2(va[i].x, va[i].y), pk2(va[i].z, va[i].w),
                         pk2(vb[i].x, vb[i].y), pk2(vb[i].z, vb[i].w)};
            *(uint4*)((char*)ctxs[0] + ((r * 1024 + lane * 16) ^ ((r & 7) << 4))) = pk4;
        }
    }
    __syncthreads();

    int cur = 0;
    #pragma unroll 1
    for (int it = 0; it < 16; ++it) {
        const int tile = blockIdx.x + it * 256;
        const int row0 = tile * 64;
        const int bidx = row0 >> 11;

        // issue next tile's loads early (latency hides under K-loop)
        if (it < 15) {
            const int nrow0 = row0 + 256 * 64;
            #pragma unroll
            for (int i = 0; i < 4; ++i) {
                const float4* src = (const float4*)(ctx + (size_t)(nrow0 + i * 16 + w) * DC + lane * 8);
                va[i] = src[0]; vb[i] = src[1];
            }
        }

        // ---- K-loop: barrier-free ----
        f32x4 acc[2][4] = {};
        #pragma unroll 2
        for (int s = 0; s < 16; ++s) {
            bf16x8 bfr[4];
            const us8* wsrc = (const us8*)(WtF + (((size_t)s * 32 + wcol * 4) * 64 + lane) * 8);
            #pragma unroll
            for (int fn = 0; fn < 4; ++fn)
                bfr[fn] = *(const bf16x8*)(wsrc + fn * 64);
            bf16x8 af[2];
            #pragma unroll
            for (int fm = 0; fm < 2; ++fm) {
                int r = wr * 32 + fm * 16 + lr;
                af[fm] = *(const bf16x8*)((const char*)ctxs[cur] +
                            ((r * 1024 + s * 64 + half * 16) ^ ((r & 7) << 4)));
            }
            #pragma unroll
            for (int fm = 0; fm < 2; ++fm)
                #pragma unroll
                for (int fn = 0; fn < 4; ++fn)
                    acc[fm][fn] = __builtin_amdgcn_mfma_f32_16x16x32_bf16(
                        af[fm], bfr[fn], acc[fm][fn], 0, 0, 0);
        }

        // ---- write next tile into the other buffer (loads done by now) ----
        if (it < 15) {
            #pragma unroll
            for (int i = 0; i < 4; ++i) {
                int r = i * 16 + w;
                uint4 pk4 = {pk2(va[i].x, va[i].y), pk2(va[i].z, va[i].w),
                             pk2(vb[i].x, vb[i].y), pk2(vb[i].z, vb[i].w)};
                *(uint4*)((char*)ctxs[cur ^ 1] + ((r * 1024 + lane * 16) ^ ((r & 7) << 4))) = pk4;
            }
        }

        // ---- epilogue: tanh fold + row reduce ----
        float wv[4], qv[4];
        #pragma unroll
        for (int fn = 0; fn < 4; ++fn) {
            int j = wcol * 64 + fn * 16 + lr;
            wv[fn] = wsc[j];
            qv[fn] = qb[bidx * DC + j];
        }
        #pragma unroll
        for (int fm = 0; fm < 2; ++fm) {
            #pragma unroll
            for (int reg = 0; reg < 4; ++reg) {
                float ssum = 0.f;
                #pragma unroll
                for (int fn = 0; fn < 4; ++fn)
                    ssum += wv[fn] * fast_tanh(qv[fn] + acc[fm][fn][reg]);
                #pragma unroll
                for (int m = 8; m >= 1; m >>= 1)
                    ssum += __shfl_xor(ssum, m, 64);
                if (lr == 0)
                    sred[wcol][wr * 32 + fm * 16 + half * 4 + reg] = ssum;
            }
        }
        __syncthreads();

        if (t < 64) {                        // wave 0: block softmax partials
            float sc = sred[0][t] + sred[1][t] + sred[2][t] + sred[3][t]
                     + sred[4][t] + sred[5][t] + sred[6][t] + sred[7][t];
            if (mask[row0 + t] != 0) sc = -1e30f;
            scores_ws[row0 + t] = sc;
            float mx = sc;
            #pragma unroll
            for (int m = 32; m >= 1; m >>= 1) mx = fmaxf(mx, __shfl_xor(mx, m, 64));
            float pe = __expf(sc - mx);
            sp[t] = pe;
            float ls = pe;
            #pragma unroll
            for (int m = 32; m >= 1; m >>= 1) ls += __shfl_xor(ls, m, 64);
            if (t == 0) {
                ml_ws[tile * 2]     = mx;
                ml_ws[tile * 2 + 1] = ls;
            }
        }
        __syncthreads();

        // ---- pv partials from LDS (split rows across thread halves) ----
        {
            int col = t & 511, rh = t >> 9;
            float a0 = 0.f;
            #pragma unroll 8
            for (int s2 = 0; s2 < 32; ++s2) {
                int r = rh * 32 + s2;
                unsigned int u = *(const unsigned short*)
                    ((const char*)ctxs[cur] + ((r * 1024 + col * 2) ^ ((r & 7) << 4)));
                a0 += sp[r] * bf2f(u);
            }
            pvpart[rh][col] = a0;
        }
        __syncthreads();
        if (t < 512)
            pv_ws[(size_t)tile * 512 + t] = pvpart[0][t] + pvpart[1][t];

        __syncthreads();
        cur ^= 1;
    }
}

// Exact cross-block softmax merge: attn + ctxv
__global__ __launch_bounds__(256) void combine_kernel(
    const float* __restrict__ pv, const float* __restrict__ ml,
    const float* __restrict__ scores,
    float* __restrict__ ctxv, float* __restrict__ attn)
{
    int b = blockIdx.x, t = threadIdx.x;
    __shared__ float sm[32], sl[32], sw[32];
    if (t < 32) {
        sm[t] = ml[(b * 32 + t) * 2];
        sl[t] = ml[(b * 32 + t) * 2 + 1];
    }
    __syncthreads();
    float mstar = -1e30f;
    #pragma unroll
    for (int i = 0; i < 32; ++i) mstar = fmaxf(mstar, sm[i]);
    if (t < 32) sw[t] = __expf(sm[t] - mstar);
    __syncthreads();
    float L = 0.f;
    #pragma unroll
    for (int i = 0; i < 32; ++i) L += sw[i] * sl[i];
    float invL = 1.f / L;

    int d0 = t * 2;
    float c0 = 0.f, c1 = 0.f;
    #pragma unroll
    for (int i = 0; i < 32; ++i) {
        float w = sw[i];
        const float2 v = *(const float2*)(pv + (size_t)(b * 32 + i) * 512 + d0);
        c0 += w * v.x; c1 += w * v.y;
    }
    ctxv[b * DC + d0]     = c0 * invL;
    ctxv[b * DC + d0 + 1] = c1 * invL;

    for (int s = t; s < S_; s += 256)
        attn[(size_t)b * S_ + s] = __expf(scores[(size_t)b * S_ + s] - mstar) * invL;
}

// x[b][i] = tanh(cat(ctxv,input) @ W_out + b_out); grid (B, 4)
__global__ __launch_bounds__(256) void out_kernel(
    const float* __restrict__ ctxv, const float* __restrict__ input,
    const float* __restrict__ W_out, const float* __restrict__ b_out,
    float* __restrict__ x)
{
    __shared__ float scm[DC + DI];
    __shared__ float part[2][128];
    int b = blockIdx.x, cg = blockIdx.y, t = threadIdx.x;
    for (int i = t; i < DC; i += 256) scm[i] = ctxv[b * DC + i];
    for (int i = t; i < DI; i += 256) scm[DC + i] = input[b * DI + i];
    __syncthreads();
    int e = cg * 128 + (t & 127);
    int dh = t >> 7;
    float a = 0.f;
    const float* wp = W_out + (size_t)(dh * 512) * DI + e;
    #pragma unroll 4
    for (int d = 0; d < 512; ++d) a += scm[dh * 512 + d] * wp[(size_t)d * DI];
    part[dh][t & 127] = a;
    __syncthreads();
    if (t < 128) {
        int ee = cg * 128 + t;
        x[b * DI + ee] = fast_tanh(b_out[ee] + part[0][t] + part[1][t]);
    }
}

extern "C" void kernel_launch(void* const* d_in, const int* in_sizes, int n_in,
                              void* d_out, int out_size, void* d_ws, size_t ws_size,
                              hipStream_t stream) {
    const float* input = (const float*)d_in[0];
    const float* ctx   = (const float*)d_in[1];
    const int*   mask  = (const int*)d_in[2];
    const float* W_in  = (const float*)d_in[3];
    const float* b_in  = (const float*)d_in[4];
    const float* W_ctx = (const float*)d_in[5];
    const float* b_ctx = (const float*)d_in[6];
    const float* wsc   = (const float*)d_in[7];
    const float* W_out = (const float*)d_in[8];
    const float* b_out = (const float*)d_in[9];

    float* x_out = (float*)d_out;               // [B, DI]
    float* attn  = (float*)d_out + B_ * DI;     // [B, S]

    const int NTILE = (B_ * S_) / 64;           // 4096 tiles

    char* ws = (char*)d_ws;
    float* qb = (float*)ws;                    ws += (size_t)B_ * DC * 4;
    unsigned short* WtF = (unsigned short*)ws; ws += (size_t)DC * DC * 2;
    float* scores_ws = (float*)ws;             ws += (size_t)B_ * S_ * 4;
    float* pv_ws = (float*)ws;                 ws += (size_t)NTILE * 512 * 4;
    float* ml_ws = (float*)ws;                 ws += (size_t)NTILE * 2 * 4;
    float* ctxv = (float*)ws;                  ws += (size_t)B_ * DC * 4;

    qb_kernel<<<dim3(B_, 4), 256, 0, stream>>>(input, W_in, b_in, b_ctx, qb);
    wt_kernel<<<(16 * 32 * 64) / 256, 256, 0, stream>>>(W_ctx, WtF);
    score_kernel<<<256, 1024, 0, stream>>>(ctx, WtF, qb, wsc, mask,
                                           scores_ws, pv_ws, ml_ws);
    combine_kernel<<<B_, 256, 0, stream>>>(pv_ws, ml_ws, scores_ws, ctxv, attn);
    out_kernel<<<dim3(B_, 4), 256, 0, stream>>>(ctxv, input, W_out, b_out, x_out);
}